// Round 3
// baseline (470.040 us; speedup 1.0000x reference)
//
#include <hip/hip_runtime.h>
#include <hip/hip_bf16.h>
#include <stdint.h>
#include <math.h>

#define NR 16384
#define DIM 768
#define KEPS 1e-8f

#define BMT 256                      // tile edge
#define BKT 64                       // K per tile
#define NB (NR / BMT)                // 64
#define KT (DIM / BKT)               // 12
#define NTILES (NB * (NB + 1) / 2)   // 2080

typedef __attribute__((ext_vector_type(4))) float f32x4;
typedef _Float16 f16x8 __attribute__((ext_vector_type(8)));

__device__ inline uint32_t fkey(float f) {
    union { float f; uint32_t u; } v; v.f = f;
    return (v.u & 0x80000000u) ? ~v.u : (v.u | 0x80000000u);
}
__device__ inline float unkey(uint32_t k) {
    union { uint32_t u; float f; } v;
    v.u = (k & 0x80000000u) ? (k ^ 0x80000000u) : ~k;
    return v.f;
}

__device__ inline void gload16(const ushort* g, const ushort* l) {
    __builtin_amdgcn_global_load_lds(
        (const __attribute__((address_space(1))) void*)g,
        (__attribute__((address_space(3))) void*)l,
        16, 0, 0);
}

// ---------------- Kernel 1: row L2-normalize, fp32 -> fp16 -------------------
__global__ __launch_bounds__(256) void k_norm(const float* __restrict__ X,
                                              ushort* __restrict__ Xn) {
    const int wid = threadIdx.x >> 6, lane = threadIdx.x & 63;
    const int row = blockIdx.x * 4 + wid;
    const float4* xr = (const float4*)(X + (size_t)row * DIM) + lane * 3;
    float4 a = xr[0], b = xr[1], c = xr[2];
    float s = a.x*a.x + a.y*a.y + a.z*a.z + a.w*a.w
            + b.x*b.x + b.y*b.y + b.z*b.z + b.w*b.w
            + c.x*c.x + c.y*c.y + c.z*c.z + c.w*c.w;
#pragma unroll
    for (int m = 32; m >= 1; m >>= 1) s += __shfl_xor(s, m);
    const float rn = 1.0f / fmaxf(sqrtf(s), KEPS);
    float v[12] = {a.x,a.y,a.z,a.w,b.x,b.y,b.z,b.w,c.x,c.y,c.z,c.w};
    uint32_t p[6];
#pragma unroll
    for (int i = 0; i < 6; ++i) {
        union { _Float16 h[2]; uint32_t u; } pk;
        pk.h[0] = (_Float16)(v[2*i] * rn);
        pk.h[1] = (_Float16)(v[2*i+1] * rn);
        p[i] = pk.u;
    }
    uint2* dst = (uint2*)(Xn + (size_t)row * DIM + lane * 12);
    dst[0] = make_uint2(p[0], p[1]);
    dst[1] = make_uint2(p[2], p[3]);
    dst[2] = make_uint2(p[4], p[5]);
}

// ---------------- Kernel 1b: init nn-max keys --------------------------------
__global__ __launch_bounds__(256) void k_init(uint32_t* __restrict__ nnkey) {
    nnkey[blockIdx.x * 256 + threadIdx.x] = fkey(-2.0f);
}

// -------- Kernel 2: 256^2 upper-tri tile, 8-phase counted-vmcnt schedule -----
// LDS: per dbuf(2) x khalf(2): A[256][32], B[256][32] fp16; 64B row stride so
// the XOR slot swizzle (sl^(row&3)) yields the measured-zero-conflict bank
// density (8 lanes / 4-bank group). Stage issue runs 3 half-stages ahead of
// the per-K-tile vmcnt(6) wait; region liveness hand-verified (see schedule
// ledger in commit message).
__global__ __launch_bounds__(512, 2) void k_maxdot(const ushort* __restrict__ Xn,
                                                   uint32_t* __restrict__ nnkey) {
    __shared__ ushort sA[2][2][256 * 32];
    __shared__ ushort sB[2][2][256 * 32];
    const int tid  = threadIdx.x;
    const int lane = tid & 63, wid = tid >> 6;
    const int l15 = lane & 15, lhi = (lane >> 4) & 3;
    const int wr = wid >> 2, wc = wid & 3;       // 2M x 4N waves

    // XCD-aware bijective swizzle (NTILES % 8 == 0)
    int t = (int)blockIdx.x;
    t = (t & 7) * (NTILES / 8) + (t >> 3);
    // decode upper-triangle tile id -> (rb, cb), cb >= rb; S(rb)=rb*(129-rb)/2
    int rb = (int)((129.0f - sqrtf(16641.0f - 8.0f * (float)t)) * 0.5f);
    if (rb < 0) rb = 0;
    if (rb > NB - 1) rb = NB - 1;
    while (rb > 0 && rb * (129 - rb) / 2 > t) --rb;
    while ((rb + 1) * (129 - (rb + 1)) / 2 <= t) ++rb;
    const int cb = rb + (t - rb * (129 - rb) / 2);
    const int rowbase = rb * BMT;
    const int colbase = cb * BMT;

    f32x4 acc[8][4];
    const f32x4 z = {0.f, 0.f, 0.f, 0.f};
#pragma unroll
    for (int i = 0; i < 8; ++i)
#pragma unroll
        for (int j = 0; j < 4; ++j) acc[i][j] = z;

    // stage one (op, khalf) region: 256 rows x 32 cols fp16 = 16KB, 2 issues
    auto STAGE = [&](ushort* region, int srcbase, int kt, int kh) {
#pragma unroll
        for (int it = 0; it < 2; ++it) {
            const int d = it * 512 + tid;          // 16B-unit dest offset
            const int R = d >> 2, sl = d & 3;
            const ushort* g = Xn + (size_t)(srcbase + R) * DIM
                            + (size_t)kt * BKT + kh * 32 + ((sl ^ (R & 3)) << 3);
            gload16(g, region + it * 4096 + wid * 512);  // wave-uniform dest
        }
    };
    // swizzled fragment read: row r, k-slice lhi within a [256][32] region
    auto RD = [&](const ushort* region, int r) -> f16x8 {
        return *(const f16x8*)(region + r * 32 + ((lhi ^ (r & 3)) << 3));
    };

    // ---- prologue: 7 half-stages, wait so kt0 fully resident ----
    STAGE(sA[0][0], rowbase, 0, 0);
    STAGE(sB[0][0], colbase, 0, 0);
    STAGE(sA[0][1], rowbase, 0, 1);
    STAGE(sB[0][1], colbase, 0, 1);
    STAGE(sA[1][0], rowbase, 1, 0);
    STAGE(sB[1][0], colbase, 1, 0);
    STAGE(sB[1][1], colbase, 1, 1);
    asm volatile("s_waitcnt vmcnt(6)" ::: "memory");   // kt0's 4 stages retired
    __builtin_amdgcn_s_barrier();

    f16x8 af[4], bg[4];
    for (int kt = 0; kt < KT; ++kt) {
        const int b = kt & 1, bn = b ^ 1;
        // ================= phase 0: kh=0, mh=0 =================
#pragma unroll
        for (int nf = 0; nf < 4; ++nf) bg[nf] = RD(sB[b][0], wc * 64 + nf * 16 + l15);
#pragma unroll
        for (int mf = 0; mf < 4; ++mf) af[mf] = RD(sA[b][0], wr * 128 + mf * 16 + l15);
        if (kt + 1 < KT) STAGE(sA[bn][1], rowbase, kt + 1, 1);
        __builtin_amdgcn_s_barrier();
        asm volatile("s_waitcnt lgkmcnt(0)" ::: "memory");
        __builtin_amdgcn_sched_barrier(0);
        __builtin_amdgcn_s_setprio(1);
#pragma unroll
        for (int mf = 0; mf < 4; ++mf)
#pragma unroll
            for (int nf = 0; nf < 4; ++nf)
                acc[mf][nf] = __builtin_amdgcn_mfma_f32_16x16x32_f16(af[mf], bg[nf], acc[mf][nf], 0, 0, 0);
        __builtin_amdgcn_s_setprio(0);
        __builtin_amdgcn_s_barrier();
        // ================= phase 1: kh=0, mh=1 (bg reused) =================
#pragma unroll
        for (int mf = 0; mf < 4; ++mf) af[mf] = RD(sA[b][0], wr * 128 + 64 + mf * 16 + l15);
        if (kt + 2 < KT) STAGE(sB[b][0], colbase, kt + 2, 0);
        __builtin_amdgcn_s_barrier();
        asm volatile("s_waitcnt lgkmcnt(0)" ::: "memory");
        __builtin_amdgcn_sched_barrier(0);
        __builtin_amdgcn_s_setprio(1);
#pragma unroll
        for (int mf = 0; mf < 4; ++mf)
#pragma unroll
            for (int nf = 0; nf < 4; ++nf)
                acc[4 + mf][nf] = __builtin_amdgcn_mfma_f32_16x16x32_f16(af[mf], bg[nf], acc[4 + mf][nf], 0, 0, 0);
        __builtin_amdgcn_s_setprio(0);
        __builtin_amdgcn_s_barrier();
        // ================= phase 2: kh=1, mh=0 =================
#pragma unroll
        for (int nf = 0; nf < 4; ++nf) bg[nf] = RD(sB[b][1], wc * 64 + nf * 16 + l15);
#pragma unroll
        for (int mf = 0; mf < 4; ++mf) af[mf] = RD(sA[b][1], wr * 128 + mf * 16 + l15);
        if (kt + 2 < KT) STAGE(sA[b][0], rowbase, kt + 2, 0);
        __builtin_amdgcn_s_barrier();
        asm volatile("s_waitcnt lgkmcnt(0)" ::: "memory");
        __builtin_amdgcn_sched_barrier(0);
        __builtin_amdgcn_s_setprio(1);
#pragma unroll
        for (int mf = 0; mf < 4; ++mf)
#pragma unroll
            for (int nf = 0; nf < 4; ++nf)
                acc[mf][nf] = __builtin_amdgcn_mfma_f32_16x16x32_f16(af[mf], bg[nf], acc[mf][nf], 0, 0, 0);
        __builtin_amdgcn_s_setprio(0);
        __builtin_amdgcn_s_barrier();
        // ================= phase 3: kh=1, mh=1 (bg reused) =================
#pragma unroll
        for (int mf = 0; mf < 4; ++mf) af[mf] = RD(sA[b][1], wr * 128 + 64 + mf * 16 + l15);
        if (kt + 2 < KT) STAGE(sB[b][1], colbase, kt + 2, 1);
        if (kt < KT - 2) { asm volatile("s_waitcnt vmcnt(6)" ::: "memory"); }
        else             { asm volatile("s_waitcnt vmcnt(0)" ::: "memory"); }
        __builtin_amdgcn_s_barrier();
        asm volatile("s_waitcnt lgkmcnt(0)" ::: "memory");
        __builtin_amdgcn_sched_barrier(0);
        __builtin_amdgcn_s_setprio(1);
#pragma unroll
        for (int mf = 0; mf < 4; ++mf)
#pragma unroll
            for (int nf = 0; nf < 4; ++nf)
                acc[4 + mf][nf] = __builtin_amdgcn_mfma_f32_16x16x32_f16(af[mf], bg[nf], acc[4 + mf][nf], 0, 0, 0);
        __builtin_amdgcn_s_setprio(0);
        __builtin_amdgcn_s_barrier();
    }

    // ---- diagonal tiles: mask self-similarity to -1 ----
    if (rb == cb) {
#pragma unroll
        for (int mf = 0; mf < 8; ++mf)
#pragma unroll
            for (int nf = 0; nf < 4; ++nf)
#pragma unroll
                for (int rr = 0; rr < 4; ++rr) {
                    const int rl = wr * 128 + mf * 16 + lhi * 4 + rr;
                    const int cl = wc * 64 + nf * 16 + l15;
                    if (rl == cl) acc[mf][nf][rr] = -1.0f;
                }
    }

    // ---- row-max: over nf regs, then 16 cols (lane bits 0..3) ----
#pragma unroll
    for (int mf = 0; mf < 8; ++mf)
#pragma unroll
        for (int rr = 0; rr < 4; ++rr) {
            float v = fmaxf(fmaxf(acc[mf][0][rr], acc[mf][1][rr]),
                            fmaxf(acc[mf][2][rr], acc[mf][3][rr]));
            v = fmaxf(v, __shfl_xor(v, 1));
            v = fmaxf(v, __shfl_xor(v, 2));
            v = fmaxf(v, __shfl_xor(v, 4));
            v = fmaxf(v, __shfl_xor(v, 8));
            if (l15 == 0) {
                const int r = rowbase + wr * 128 + mf * 16 + lhi * 4 + rr;
                atomicMax(&nnkey[r], fkey(v));
            }
        }

    // ---- col-max: over mf,rr regs, then 4 row-groups (lane bits 4,5) ----
#pragma unroll
    for (int nf = 0; nf < 4; ++nf) {
        float v = -2.0f;
#pragma unroll
        for (int mf = 0; mf < 8; ++mf)
#pragma unroll
            for (int rr = 0; rr < 4; ++rr) v = fmaxf(v, acc[mf][nf][rr]);
        v = fmaxf(v, __shfl_xor(v, 16));
        v = fmaxf(v, __shfl_xor(v, 32));
        if (lhi == 0 && (lane >> 4) == 0) {
            const int c = colbase + wc * 64 + nf * 16 + l15;
            atomicMax(&nnkey[c], fkey(v));
        }
    }
}

// ---------------- Kernel 3: compute loss from nn-max keys --------------------
__global__ __launch_bounds__(256) void k_loss(const uint32_t* __restrict__ nnkey,
                                              float* __restrict__ out) {
    float local = 0.0f;
    for (int r = threadIdx.x; r < NR; r += 256) {
        const float m = unkey(nnkey[r]);
        const float d = sqrtf(fmaxf(2.0f - 2.0f * m, 0.0f));
        local += logf(d + KEPS);
    }
#pragma unroll
    for (int m = 32; m >= 1; m >>= 1) local += __shfl_xor(local, m);
    __shared__ float red[4];
    const int lane = threadIdx.x & 63, wid = threadIdx.x >> 6;
    if (lane == 0) red[wid] = local;
    __syncthreads();
    if (threadIdx.x == 0)
        out[0] = -(red[0] + red[1] + red[2] + red[3]) / (float)NR;
}

extern "C" void kernel_launch(void* const* d_in, const int* in_sizes, int n_in,
                              void* d_out, int out_size, void* d_ws, size_t ws_size,
                              hipStream_t stream) {
    const float* X = (const float*)d_in[0];
    float* out = (float*)d_out;
    ushort* Xn = (ushort*)d_ws;                                        // 24 MiB fp16
    uint32_t* nnkey = (uint32_t*)((char*)d_ws + (size_t)NR * DIM * 2); // 64 KiB

    k_norm<<<NR / 4, 256, 0, stream>>>(X, Xn);
    k_init<<<NR / 256, 256, 0, stream>>>(nnkey);
    k_maxdot<<<NTILES, 512, 0, stream>>>(Xn, nnkey);
    k_loss<<<1, 256, 0, stream>>>(nnkey, out);
}

// Round 4
// 458.562 us; speedup vs baseline: 1.0250x; 1.0250x over previous
//
#include <hip/hip_runtime.h>
#include <hip/hip_bf16.h>
#include <stdint.h>
#include <math.h>

#define NR 16384
#define DIM 768
#define KEPS 1e-8f

#define BMT 256                      // tile edge
#define BKT 64                       // K per tile
#define NB (NR / BMT)                // 64
#define KT (DIM / BKT)               // 12
#define NTILES (NB * (NB + 1) / 2)   // 2080

typedef __attribute__((ext_vector_type(4))) float f32x4;
typedef _Float16 f16x8 __attribute__((ext_vector_type(8)));

__device__ inline uint32_t fkey(float f) {
    union { float f; uint32_t u; } v; v.f = f;
    return (v.u & 0x80000000u) ? ~v.u : (v.u | 0x80000000u);
}
__device__ inline float unkey(uint32_t k) {
    union { uint32_t u; float f; } v;
    v.u = (k & 0x80000000u) ? (k ^ 0x80000000u) : ~k;
    return v.f;
}

__device__ inline void gload16(const ushort* g, const ushort* l) {
    __builtin_amdgcn_global_load_lds(
        (const __attribute__((address_space(1))) void*)g,
        (__attribute__((address_space(3))) void*)l,
        16, 0, 0);
}

// ---------------- Kernel 1: row L2-normalize, fp32 -> fp16 -------------------
__global__ __launch_bounds__(256) void k_norm(const float* __restrict__ X,
                                              ushort* __restrict__ Xn) {
    const int wid = threadIdx.x >> 6, lane = threadIdx.x & 63;
    const int row = blockIdx.x * 4 + wid;
    const float4* xr = (const float4*)(X + (size_t)row * DIM) + lane * 3;
    float4 a = xr[0], b = xr[1], c = xr[2];
    float s = a.x*a.x + a.y*a.y + a.z*a.z + a.w*a.w
            + b.x*b.x + b.y*b.y + b.z*b.z + b.w*b.w
            + c.x*c.x + c.y*c.y + c.z*c.z + c.w*c.w;
#pragma unroll
    for (int m = 32; m >= 1; m >>= 1) s += __shfl_xor(s, m);
    const float rn = 1.0f / fmaxf(sqrtf(s), KEPS);
    float v[12] = {a.x,a.y,a.z,a.w,b.x,b.y,b.z,b.w,c.x,c.y,c.z,c.w};
    uint32_t p[6];
#pragma unroll
    for (int i = 0; i < 6; ++i) {
        union { _Float16 h[2]; uint32_t u; } pk;
        pk.h[0] = (_Float16)(v[2*i] * rn);
        pk.h[1] = (_Float16)(v[2*i+1] * rn);
        p[i] = pk.u;
    }
    uint2* dst = (uint2*)(Xn + (size_t)row * DIM + lane * 12);
    dst[0] = make_uint2(p[0], p[1]);
    dst[1] = make_uint2(p[2], p[3]);
    dst[2] = make_uint2(p[4], p[5]);
}

// ---------------- Kernel 1b: init nn-max keys --------------------------------
__global__ __launch_bounds__(256) void k_init(uint32_t* __restrict__ nnkey) {
    nnkey[blockIdx.x * 256 + threadIdx.x] = fkey(-2.0f);
}

// -------- Kernel 2: 256^2 upper-tri tile, 8-phase counted-vmcnt schedule -----
// LDS regions [256][32] fp16, 64B row stride -> banks repeat every 2 rows.
// Slot swizzle keys on (r>>1)&3 so bank_start = 16*(r&1) + 4*(lhi^((r>>1)&3))
// bijects 16 consecutive rows onto 8 bank positions x2 = free 2-way aliasing
// (R3's r&3 swizzle was a 4-way conflict: SQ_LDS_BANK_CONFLICT 1.9e7).
// Stage issue runs 3 half-stages ahead of the per-K-tile vmcnt(6) wait.
__global__ __launch_bounds__(512, 2) void k_maxdot(const ushort* __restrict__ Xn,
                                                   uint32_t* __restrict__ nnkey) {
    __shared__ ushort sA[2][2][256 * 32];
    __shared__ ushort sB[2][2][256 * 32];
    const int tid  = threadIdx.x;
    const int lane = tid & 63, wid = tid >> 6;
    const int l15 = lane & 15, lhi = (lane >> 4) & 3;
    const int wr = wid >> 2, wc = wid & 3;       // 2M x 4N waves

    // XCD-aware bijective swizzle (NTILES % 8 == 0)
    int t = (int)blockIdx.x;
    t = (t & 7) * (NTILES / 8) + (t >> 3);
    // decode upper-triangle tile id -> (rb, cb), cb >= rb; S(rb)=rb*(129-rb)/2
    int rb = (int)((129.0f - sqrtf(16641.0f - 8.0f * (float)t)) * 0.5f);
    if (rb < 0) rb = 0;
    if (rb > NB - 1) rb = NB - 1;
    while (rb > 0 && rb * (129 - rb) / 2 > t) --rb;
    while ((rb + 1) * (129 - (rb + 1)) / 2 <= t) ++rb;
    const int cb = rb + (t - rb * (129 - rb) / 2);
    const int rowbase = rb * BMT;
    const int colbase = cb * BMT;

    f32x4 acc[8][4];
    const f32x4 z = {0.f, 0.f, 0.f, 0.f};
#pragma unroll
    for (int i = 0; i < 8; ++i)
#pragma unroll
        for (int j = 0; j < 4; ++j) acc[i][j] = z;

    // stage one (op, khalf) region: 256 rows x 32 cols fp16 = 16KB, 2 issues
    auto STAGE = [&](ushort* region, int srcbase, int kt, int kh) {
#pragma unroll
        for (int it = 0; it < 2; ++it) {
            const int d = it * 512 + tid;          // 16B-unit dest offset
            const int R = d >> 2, sl = d & 3;
            const ushort* g = Xn + (size_t)(srcbase + R) * DIM
                            + (size_t)kt * BKT + kh * 32 + ((sl ^ ((R >> 1) & 3)) << 3);
            gload16(g, region + it * 4096 + wid * 512);  // wave-uniform dest
        }
    };
    // swizzled fragment read: row r, k-slice lhi within a [256][32] region
    auto RD = [&](const ushort* region, int r) -> f16x8 {
        return *(const f16x8*)(region + r * 32 + ((lhi ^ ((r >> 1) & 3)) << 3));
    };

    // ---- prologue: 7 half-stages, wait so kt0 fully resident ----
    STAGE(sA[0][0], rowbase, 0, 0);
    STAGE(sB[0][0], colbase, 0, 0);
    STAGE(sA[0][1], rowbase, 0, 1);
    STAGE(sB[0][1], colbase, 0, 1);
    STAGE(sA[1][0], rowbase, 1, 0);
    STAGE(sB[1][0], colbase, 1, 0);
    STAGE(sB[1][1], colbase, 1, 1);
    asm volatile("s_waitcnt vmcnt(6)" ::: "memory");   // kt0's 4 stages retired
    __builtin_amdgcn_s_barrier();

    f16x8 af[4], bg[4];
    for (int kt = 0; kt < KT; ++kt) {
        const int b = kt & 1, bn = b ^ 1;
        // ================= phase 0: kh=0, mh=0 =================
#pragma unroll
        for (int nf = 0; nf < 4; ++nf) bg[nf] = RD(sB[b][0], wc * 64 + nf * 16 + l15);
#pragma unroll
        for (int mf = 0; mf < 4; ++mf) af[mf] = RD(sA[b][0], wr * 128 + mf * 16 + l15);
        if (kt + 1 < KT) STAGE(sA[bn][1], rowbase, kt + 1, 1);
        __builtin_amdgcn_s_barrier();
        asm volatile("s_waitcnt lgkmcnt(0)" ::: "memory");
        __builtin_amdgcn_sched_barrier(0);
        __builtin_amdgcn_s_setprio(1);
#pragma unroll
        for (int mf = 0; mf < 4; ++mf)
#pragma unroll
            for (int nf = 0; nf < 4; ++nf)
                acc[mf][nf] = __builtin_amdgcn_mfma_f32_16x16x32_f16(af[mf], bg[nf], acc[mf][nf], 0, 0, 0);
        __builtin_amdgcn_s_setprio(0);
        __builtin_amdgcn_s_barrier();
        // ================= phase 1: kh=0, mh=1 (bg reused) =================
#pragma unroll
        for (int mf = 0; mf < 4; ++mf) af[mf] = RD(sA[b][0], wr * 128 + 64 + mf * 16 + l15);
        if (kt + 2 < KT) STAGE(sB[b][0], colbase, kt + 2, 0);
        __builtin_amdgcn_s_barrier();
        asm volatile("s_waitcnt lgkmcnt(0)" ::: "memory");
        __builtin_amdgcn_sched_barrier(0);
        __builtin_amdgcn_s_setprio(1);
#pragma unroll
        for (int mf = 0; mf < 4; ++mf)
#pragma unroll
            for (int nf = 0; nf < 4; ++nf)
                acc[4 + mf][nf] = __builtin_amdgcn_mfma_f32_16x16x32_f16(af[mf], bg[nf], acc[4 + mf][nf], 0, 0, 0);
        __builtin_amdgcn_s_setprio(0);
        __builtin_amdgcn_s_barrier();
        // ================= phase 2: kh=1, mh=0 =================
#pragma unroll
        for (int nf = 0; nf < 4; ++nf) bg[nf] = RD(sB[b][1], wc * 64 + nf * 16 + l15);
#pragma unroll
        for (int mf = 0; mf < 4; ++mf) af[mf] = RD(sA[b][1], wr * 128 + mf * 16 + l15);
        if (kt + 2 < KT) STAGE(sA[b][0], rowbase, kt + 2, 0);
        __builtin_amdgcn_s_barrier();
        asm volatile("s_waitcnt lgkmcnt(0)" ::: "memory");
        __builtin_amdgcn_sched_barrier(0);
        __builtin_amdgcn_s_setprio(1);
#pragma unroll
        for (int mf = 0; mf < 4; ++mf)
#pragma unroll
            for (int nf = 0; nf < 4; ++nf)
                acc[mf][nf] = __builtin_amdgcn_mfma_f32_16x16x32_f16(af[mf], bg[nf], acc[mf][nf], 0, 0, 0);
        __builtin_amdgcn_s_setprio(0);
        __builtin_amdgcn_s_barrier();
        // ================= phase 3: kh=1, mh=1 (bg reused) =================
#pragma unroll
        for (int mf = 0; mf < 4; ++mf) af[mf] = RD(sA[b][1], wr * 128 + 64 + mf * 16 + l15);
        if (kt + 2 < KT) STAGE(sB[b][1], colbase, kt + 2, 1);
        if (kt < KT - 2) { asm volatile("s_waitcnt vmcnt(6)" ::: "memory"); }
        else             { asm volatile("s_waitcnt vmcnt(0)" ::: "memory"); }
        __builtin_amdgcn_s_barrier();
        asm volatile("s_waitcnt lgkmcnt(0)" ::: "memory");
        __builtin_amdgcn_sched_barrier(0);
        __builtin_amdgcn_s_setprio(1);
#pragma unroll
        for (int mf = 0; mf < 4; ++mf)
#pragma unroll
            for (int nf = 0; nf < 4; ++nf)
                acc[4 + mf][nf] = __builtin_amdgcn_mfma_f32_16x16x32_f16(af[mf], bg[nf], acc[4 + mf][nf], 0, 0, 0);
        __builtin_amdgcn_s_setprio(0);
        __builtin_amdgcn_s_barrier();
    }

    // ---- diagonal tiles: mask self-similarity to -1 ----
    if (rb == cb) {
#pragma unroll
        for (int mf = 0; mf < 8; ++mf)
#pragma unroll
            for (int nf = 0; nf < 4; ++nf)
#pragma unroll
                for (int rr = 0; rr < 4; ++rr) {
                    const int rl = wr * 128 + mf * 16 + lhi * 4 + rr;
                    const int cl = wc * 64 + nf * 16 + l15;
                    if (rl == cl) acc[mf][nf][rr] = -1.0f;
                }
    }

    // ---- row-max: over nf regs, then 16 cols (lane bits 0..3) ----
#pragma unroll
    for (int mf = 0; mf < 8; ++mf)
#pragma unroll
        for (int rr = 0; rr < 4; ++rr) {
            float v = fmaxf(fmaxf(acc[mf][0][rr], acc[mf][1][rr]),
                            fmaxf(acc[mf][2][rr], acc[mf][3][rr]));
            v = fmaxf(v, __shfl_xor(v, 1));
            v = fmaxf(v, __shfl_xor(v, 2));
            v = fmaxf(v, __shfl_xor(v, 4));
            v = fmaxf(v, __shfl_xor(v, 8));
            if (l15 == 0) {
                const int r = rowbase + wr * 128 + mf * 16 + lhi * 4 + rr;
                atomicMax(&nnkey[r], fkey(v));
            }
        }

    // ---- col-max: over mf,rr regs, then 4 row-groups (lane bits 4,5) ----
#pragma unroll
    for (int nf = 0; nf < 4; ++nf) {
        float v = -2.0f;
#pragma unroll
        for (int mf = 0; mf < 8; ++mf)
#pragma unroll
            for (int rr = 0; rr < 4; ++rr) v = fmaxf(v, acc[mf][nf][rr]);
        v = fmaxf(v, __shfl_xor(v, 16));
        v = fmaxf(v, __shfl_xor(v, 32));
        if (lhi == 0 && (lane >> 4) == 0) {
            const int c = colbase + wc * 64 + nf * 16 + l15;
            atomicMax(&nnkey[c], fkey(v));
        }
    }
}

// ---------------- Kernel 3: compute loss from nn-max keys --------------------
__global__ __launch_bounds__(256) void k_loss(const uint32_t* __restrict__ nnkey,
                                              float* __restrict__ out) {
    float local = 0.0f;
    for (int r = threadIdx.x; r < NR; r += 256) {
        const float m = unkey(nnkey[r]);
        const float d = sqrtf(fmaxf(2.0f - 2.0f * m, 0.0f));
        local += logf(d + KEPS);
    }
#pragma unroll
    for (int m = 32; m >= 1; m >>= 1) local += __shfl_xor(local, m);
    __shared__ float red[4];
    const int lane = threadIdx.x & 63, wid = threadIdx.x >> 6;
    if (lane == 0) red[wid] = local;
    __syncthreads();
    if (threadIdx.x == 0)
        out[0] = -(red[0] + red[1] + red[2] + red[3]) / (float)NR;
}

extern "C" void kernel_launch(void* const* d_in, const int* in_sizes, int n_in,
                              void* d_out, int out_size, void* d_ws, size_t ws_size,
                              hipStream_t stream) {
    const float* X = (const float*)d_in[0];
    float* out = (float*)d_out;
    ushort* Xn = (ushort*)d_ws;                                        // 24 MiB fp16
    uint32_t* nnkey = (uint32_t*)((char*)d_ws + (size_t)NR * DIM * 2); // 64 KiB

    k_norm<<<NR / 4, 256, 0, stream>>>(X, Xn);
    k_init<<<NR / 256, 256, 0, stream>>>(nnkey);
    k_maxdot<<<NTILES, 512, 0, stream>>>(Xn, nnkey);
    k_loss<<<1, 256, 0, stream>>>(nnkey, out);
}

// Round 5
// 315.090 us; speedup vs baseline: 1.4918x; 1.4553x over previous
//
#include <hip/hip_runtime.h>
#include <hip/hip_bf16.h>
#include <stdint.h>
#include <math.h>

#define NR 16384
#define DIM 768
#define KEPS 1e-8f

#define BM 128          // tile edge
#define BK 64           // staged K per tile
#define NB (NR / BM)    // 128 row/col blocks
#define KT (DIM / BK)   // 12 k-tiles
#define NTILES (NB * (NB + 1) / 2)   // 8256 upper-triangle tiles

typedef __attribute__((ext_vector_type(4))) float f32x4;
typedef _Float16 f16x8 __attribute__((ext_vector_type(8)));

__device__ inline uint32_t fkey(float f) {
    union { float f; uint32_t u; } v; v.f = f;
    return (v.u & 0x80000000u) ? ~v.u : (v.u | 0x80000000u);
}
__device__ inline float unkey(uint32_t k) {
    union { uint32_t u; float f; } v;
    v.u = (k & 0x80000000u) ? (k ^ 0x80000000u) : ~k;
    return v.f;
}

__device__ inline void gload16(const ushort* g, const ushort* l) {
    __builtin_amdgcn_global_load_lds(
        (const __attribute__((address_space(1))) void*)g,
        (__attribute__((address_space(3))) void*)l,
        16, 0, 0);
}

// ---------------- Kernel 1: row L2-normalize, fp32 -> fp16 -------------------
__global__ __launch_bounds__(256) void k_norm(const float* __restrict__ X,
                                              ushort* __restrict__ Xn) {
    const int wid = threadIdx.x >> 6, lane = threadIdx.x & 63;
    const int row = blockIdx.x * 4 + wid;
    const float4* xr = (const float4*)(X + (size_t)row * DIM) + lane * 3;
    float4 a = xr[0], b = xr[1], c = xr[2];
    float s = a.x*a.x + a.y*a.y + a.z*a.z + a.w*a.w
            + b.x*b.x + b.y*b.y + b.z*b.z + b.w*b.w
            + c.x*c.x + c.y*c.y + c.z*c.z + c.w*c.w;
#pragma unroll
    for (int m = 32; m >= 1; m >>= 1) s += __shfl_xor(s, m);
    const float rn = 1.0f / fmaxf(sqrtf(s), KEPS);
    float v[12] = {a.x,a.y,a.z,a.w,b.x,b.y,b.z,b.w,c.x,c.y,c.z,c.w};
    uint32_t p[6];
#pragma unroll
    for (int i = 0; i < 6; ++i) {
        union { _Float16 h[2]; uint32_t u; } pk;
        pk.h[0] = (_Float16)(v[2*i] * rn);
        pk.h[1] = (_Float16)(v[2*i+1] * rn);
        p[i] = pk.u;
    }
    uint2* dst = (uint2*)(Xn + (size_t)row * DIM + lane * 12);
    dst[0] = make_uint2(p[0], p[1]);
    dst[1] = make_uint2(p[2], p[3]);
    dst[2] = make_uint2(p[4], p[5]);
}

// ---------------- Kernel 1b: init nn-max keys --------------------------------
__global__ __launch_bounds__(256) void k_init(uint32_t* __restrict__ nnkey) {
    nnkey[blockIdx.x * 256 + threadIdx.x] = fkey(-2.0f);
}

// -------- Kernel 2: m97-style 128^2 upper-tri tile, single-buffer, 4 blk/CU --
// Short-K regime (12 K-steps): TLP > pipelining. Single 32KB LDS buffer ->
// 4 blocks/CU; the __syncthreads vmcnt(0) drain is hidden by co-resident
// blocks (m114 mechanism). Swizzle identical to R1/R2 (measured 0 conflicts).
__global__ __launch_bounds__(256, 4) void k_maxdot(const ushort* __restrict__ Xn,
                                                   uint32_t* __restrict__ nnkey) {
    __shared__ ushort lA[BM * BK];
    __shared__ ushort lB[BM * BK];
    const int tid  = threadIdx.x;
    const int lane = tid & 63, wid = tid >> 6;
    const int wr = wid >> 1, wc = wid & 1;
    const int l15 = lane & 15, lhi = lane >> 4;

    // XCD-chunked bijective swizzle (NTILES % 8 == 0) for per-XCD L2 locality
    int t = (int)blockIdx.x;
    t = (t & 7) * (NTILES / 8) + (t >> 3);
    // decode linear tile id -> (rb, cb), cb >= rb   [S(rb) = rb*(257-rb)/2]
    float disc = 66049.0f - 8.0f * (float)t;        // 257^2 - 8t
    int rb = (int)((257.0f - sqrtf(disc)) * 0.5f);
    if (rb > NB - 1) rb = NB - 1;
    if (rb < 0) rb = 0;
    while (rb > 0 && rb * (257 - rb) / 2 > t) --rb;
    while ((rb + 1) * (257 - (rb + 1)) / 2 <= t) ++rb;
    const int cb = rb + (t - rb * (257 - rb) / 2);
    const int rowbase = rb * BM;
    const int colbase = cb * BM;
    const bool diag = (rb == cb);

    const int s_row  = tid >> 3;      // row within 32-row chunk
    const int s_slot = tid & 7;       // 8-elem slot within 64-elem row

    f32x4 acc[4][4];
    const f32x4 z = {0.f, 0.f, 0.f, 0.f};
#pragma unroll
    for (int i = 0; i < 4; ++i)
#pragma unroll
        for (int j = 0; j < 4; ++j) acc[i][j] = z;

    for (int kt = 0; kt < KT; ++kt) {
        // ---- stage kt (XOR-swizzled source, linear LDS dest) ----
#pragma unroll
        for (int it = 0; it < 4; ++it) {
            const int r = it * 32 + s_row;
            const size_t koff = (size_t)kt * BK + (size_t)((s_slot ^ (r & 7)) << 3);
            gload16(Xn + (size_t)(rowbase + r) * DIM + koff, &lA[it * 2048 + wid * 512]);
            gload16(Xn + (size_t)(colbase + r) * DIM + koff, &lB[it * 2048 + wid * 512]);
        }
        __syncthreads();     // compiler emits vmcnt(0) lgkmcnt(0) drain here
#pragma unroll
        for (int ks = 0; ks < 2; ++ks) {
            f16x8 af[4], bg[4];
#pragma unroll
            for (int mf = 0; mf < 4; ++mf) {
                const int r = wr * 64 + mf * 16 + l15;
                const int slot = (ks * 4 + lhi) ^ (r & 7);
                af[mf] = *(const f16x8*)(lA + r * BK + slot * 8);
            }
#pragma unroll
            for (int nf = 0; nf < 4; ++nf) {
                const int r = wc * 64 + nf * 16 + l15;
                const int slot = (ks * 4 + lhi) ^ (r & 7);
                bg[nf] = *(const f16x8*)(lB + r * BK + slot * 8);
            }
#pragma unroll
            for (int mf = 0; mf < 4; ++mf)
#pragma unroll
                for (int nf = 0; nf < 4; ++nf)
                    acc[mf][nf] = __builtin_amdgcn_mfma_f32_16x16x32_f16(
                        af[mf], bg[nf], acc[mf][nf], 0, 0, 0);
        }
        __syncthreads();     // all reads of this buffer done before next STAGE
    }

    // diagonal tiles: mask self-similarity to -1 (reference semantics)
    if (diag) {
#pragma unroll
        for (int mf = 0; mf < 4; ++mf)
#pragma unroll
            for (int nf = 0; nf < 4; ++nf)
#pragma unroll
                for (int rr = 0; rr < 4; ++rr) {
                    const int rl = wr * 64 + mf * 16 + lhi * 4 + rr;
                    const int cl = wc * 64 + nf * 16 + l15;
                    if (rl == cl) acc[mf][nf][rr] = -1.0f;
                }
    }

    // ---- row-max: reduce over nf (regs) then 16 cols (lane bits 0..3) ----
#pragma unroll
    for (int mf = 0; mf < 4; ++mf) {
#pragma unroll
        for (int rr = 0; rr < 4; ++rr) {
            float v = fmaxf(fmaxf(acc[mf][0][rr], acc[mf][1][rr]),
                            fmaxf(acc[mf][2][rr], acc[mf][3][rr]));
            v = fmaxf(v, __shfl_xor(v, 1));
            v = fmaxf(v, __shfl_xor(v, 2));
            v = fmaxf(v, __shfl_xor(v, 4));
            v = fmaxf(v, __shfl_xor(v, 8));
            if (l15 == 0) {
                const int r = rowbase + wr * 64 + mf * 16 + lhi * 4 + rr;
                atomicMax(&nnkey[r], fkey(v));
            }
        }
    }

    // ---- col-max: reduce over mf,rr (regs) then 4 row-groups (bits 4,5) ----
#pragma unroll
    for (int nf = 0; nf < 4; ++nf) {
        float v = -2.0f;
#pragma unroll
        for (int mf = 0; mf < 4; ++mf)
#pragma unroll
            for (int rr = 0; rr < 4; ++rr) v = fmaxf(v, acc[mf][nf][rr]);
        v = fmaxf(v, __shfl_xor(v, 16));
        v = fmaxf(v, __shfl_xor(v, 32));
        if (lhi == 0) {
            const int c = colbase + wc * 64 + nf * 16 + l15;
            atomicMax(&nnkey[c], fkey(v));
        }
    }
}

// ---------------- Kernel 3: compute loss from nn-max keys --------------------
__global__ __launch_bounds__(256) void k_loss(const uint32_t* __restrict__ nnkey,
                                              float* __restrict__ out) {
    float local = 0.0f;
    for (int r = threadIdx.x; r < NR; r += 256) {
        const float m = unkey(nnkey[r]);
        const float d = sqrtf(fmaxf(2.0f - 2.0f * m, 0.0f));
        local += logf(d + KEPS);
    }
#pragma unroll
    for (int m = 32; m >= 1; m >>= 1) local += __shfl_xor(local, m);
    __shared__ float red[4];
    const int lane = threadIdx.x & 63, wid = threadIdx.x >> 6;
    if (lane == 0) red[wid] = local;
    __syncthreads();
    if (threadIdx.x == 0)
        out[0] = -(red[0] + red[1] + red[2] + red[3]) / (float)NR;
}

extern "C" void kernel_launch(void* const* d_in, const int* in_sizes, int n_in,
                              void* d_out, int out_size, void* d_ws, size_t ws_size,
                              hipStream_t stream) {
    const float* X = (const float*)d_in[0];
    float* out = (float*)d_out;
    ushort* Xn = (ushort*)d_ws;                                    // 24 MiB fp16
    uint32_t* nnkey = (uint32_t*)((char*)d_ws + (size_t)NR * DIM * 2); // 64 KiB

    k_norm<<<NR / 4, 256, 0, stream>>>(X, Xn);
    k_init<<<NR / 256, 256, 0, stream>>>(nnkey);
    k_maxdot<<<NTILES, 256, 0, stream>>>(Xn, nnkey);
    k_loss<<<1, 256, 0, stream>>>(nnkey, out);
}